// Round 13
// baseline (337.657 us; speedup 1.0000x reference)
//
#include <hip/hip_runtime.h>
#include <hip/hip_fp16.h>
#include <cstdint>
#include <cstddef>

#define GLOBAL_AS __attribute__((address_space(1)))
#define LDS_AS    __attribute__((address_space(3)))

typedef __attribute__((ext_vector_type(8)))  _Float16 f16x8;
typedef __attribute__((ext_vector_type(16))) float    f32x16;

__device__ __forceinline__ void gload_lds16(const void* g, void* l) {
    __builtin_amdgcn_global_load_lds((const GLOBAL_AS void*)g,
                                     (LDS_AS void*)l, 16, 0, 0);
}

// fp16 quantizer == reference fp_quantize_ste(exp=5, sig=10): RNE + saturate.
__device__ __forceinline__ __half qcvt(float x) {
    x = fminf(fmaxf(x, -65504.f), 65504.f);
    return __float2half(x);   // v_cvt_f16_f32: RNE, subnormals handled
}

// Fused quantization of x and w (both f32 -> f16), one launch, grid-stride.
__global__ void quant_xw_f32_to_f16(const float* __restrict__ xin, int x4,
                                    const float* __restrict__ win, int w4,
                                    __half* __restrict__ xout,
                                    __half* __restrict__ wout) {
    const int stride = gridDim.x * blockDim.x;
    const int tot = x4 + w4;
    for (int i = blockIdx.x * blockDim.x + threadIdx.x; i < tot; i += stride) {
        const bool isx = (i < x4);
        const int  j   = isx ? i : i - x4;
        const float4 f = reinterpret_cast<const float4*>(isx ? xin : win)[j];
        union { __half h[4]; uint2 u; } p;
        p.h[0] = qcvt(f.x);
        p.h[1] = qcvt(f.y);
        p.h[2] = qcvt(f.z);
        p.h[3] = qcvt(f.w);
        reinterpret_cast<uint2*>(isx ? xout : wout)[j] = p.u;
    }
}

// ---------------------------------------------------------------------------
// 256x256 tile, BK=64, 8 waves (2Mx4N), 4 phases/K-tile, R12 schedule,
// mfma_f32_32x32x16_f16 (floor 2066 vs 2483 cyc/tile).
// ROUND 13: FRAGMENT-ORDER LDS. Each 16KB half-region = 16 fragments x 1KB;
// fragment f = blk*4 + kk holds lane l's 16B at f*1024 + l*16. Every
// ds_read_b128 is base + lane*16 + imm -> LINEAR (conflict-free like the
// DMA write). The permutation lives in the staging GLOBAL address (m173):
// thread t, call c feeds fragment f = c*8 + wid, lane l = t&63:
//   srow = (wid>>2)*32 + (l&31)        (call1: +64 via rstep)
//   scb  = (wid&3)*32  + (l>>5)*16     (bytes)
// Bijective onto (rows 0..127) x (k-bytes 0..127) per half — checked both
// directions. Fragment contents identical to R11's HW-verified mapping:
//   A/B operand: row/col = l&31, k = (l>>5)*8 + j (mfma 32x32x16 f16)
//   C/D (m74/m101): col = lane&31, row = (reg&3) + 8*(reg>>2) + 4*(lane>>5)
//
// Phases (R12): P0=(A0,B0) reads af<-A0(8); P1=(A0,B1) reads B1(4);
// P2=(A1,B1) reads af<-A1(8); P3=(A1,B0) pre-reads next B0(4) after
// vmcnt(6)+barrier. Staging: P0:B0(t+1)->nxt P1:A0(t+2) P2:B1(t+2) P3:A1(t+2).
// lgkm ledgers: P0 entry 4(B0') +8 -> W4/W0. P1 +4 -> W2/W0. P2 +8 -> W4/W0.
// P3: issue 4, no wait (carried). vmcnt(6)@P3 retires all of tile t+1.
// ---------------------------------------------------------------------------
__global__ __launch_bounds__(512, 2) void gemm_f16_fragorder(
    const __half* __restrict__ A, const __half* __restrict__ B,
    const float* __restrict__ bias, float* __restrict__ C,
    int M, int N, int K)
{
    __shared__ __align__(16) __half lds[2][2][2][8192];   // 128 KiB
    // [buf](64KiB) [op A=0/B=1](32KiB) [half](16KiB fragment-order region)

    const int tid  = threadIdx.x;
    const int lane = tid & 63;
    const int wid  = tid >> 6;     // 8 waves
    const int wr   = wid >> 2;     // 0..1 (M)
    const int wc   = wid & 3;      // 0..3 (N)
    const int lr   = lane & 31;
    const int hi   = lane >> 5;

    // bijective XCD swizzle (m204)
    const int nwg = gridDim.x;
    const int qq = nwg >> 3, rr = nwg & 7;
    const int xcd = blockIdx.x & 7, idx = blockIdx.x >> 3;
    const int wgid = (xcd < rr ? xcd * (qq + 1)
                               : rr * (qq + 1) + (xcd - rr) * qq) + idx;
    const int nbn = N >> 8;
    const int tile_m = (wgid / nbn) << 8;
    const int tile_n = (wgid % nbn) << 8;

    // ---- staging source coords (fragment-order inverse, per thread) ----
    const int srow = ((wid >> 2) << 5) + lr;              // 0..63
    const int scb  = ((wid & 3) << 5) + (hi << 4);        // col byte 0..112
    const char* gA0 = (const char*)A + (size_t)(tile_m + srow) * K * 2 + scb;
    const char* gB0 = (const char*)B + (size_t)(tile_n + srow) * K * 2 + scb;
    const size_t rstep = (size_t)64  * K * 2;   // +64 rows (call 1)
    const size_t hstep = (size_t)128 * K * 2;   // +1 half (128 rows)
    const int ldst = tid * 16;                  // linear LDS dest byte

    // ---- fragment-read bases: linear lane*16 (conflict-free) ----
    const uint32_t lds0 = (uint32_t)(size_t)(LDS_AS const char*)&lds[0][0][0][0];
    const uint32_t baseA0 = lds0 + (uint32_t)(wr * 8192 + lane * 16);
    const uint32_t baseA1 = baseA0 + 65536u;
    const uint32_t baseB0 = lds0 + 32768u + (uint32_t)(wc * 4096 + lane * 16);
    const uint32_t baseB1 = baseB0 + 65536u;
    // A frag (mm,kk) of half h: offset h*16384 + mm*4096 + kk*1024
    // B frag (kk)    of half h: offset h*16384 + kk*1024

    f32x16 acc[2][2][2];   // [qa][qb][mm]
#pragma unroll
    for (int qa = 0; qa < 2; ++qa)
#pragma unroll
        for (int qb = 0; qb < 2; ++qb)
#pragma unroll
            for (int mm = 0; mm < 2; ++mm)
#pragma unroll
                for (int e = 0; e < 16; ++e)
                    acc[qa][qb][mm][e] = 0.f;

    f16x8 af[2][4];    // A fragments [mm][kk] of current half
    f16x8 bfP[4];      // B set ping [kk]
    f16x8 bfQ[4];      // B set pong [kk]

#define STAGE_A(bufi, h, kt) do {                                          \
        char* l_ = (char*)(&lds[bufi][0][h][0]) + ldst;                    \
        const char* g_ = gA0 + (size_t)(kt) * 128 + ((h) ? hstep : 0);     \
        gload_lds16(g_, l_);                                               \
        gload_lds16(g_ + rstep, l_ + 8192);                                \
    } while (0)

#define STAGE_B(bufi, h, kt) do {                                          \
        char* l_ = (char*)(&lds[bufi][1][h][0]) + ldst;                    \
        const char* g_ = gB0 + (size_t)(kt) * 128 + ((h) ? hstep : 0);     \
        gload_lds16(g_, l_);                                               \
        gload_lds16(g_ + rstep, l_ + 8192);                                \
    } while (0)

// inline-asm ds_read_b128, base VGPR + constant offset via %c
#define DSR(dst, base, OFF)                                                \
    asm volatile("ds_read_b128 %0, %1 offset:%c2"                          \
                 : "=v"(dst) : "v"(base), "i"(OFF))

// 8 A reads: mm0 kk0..3 first (retired by WAITL(4)), then mm1 kk0..3
#define LDGA(BASE, H) do {                                                 \
        DSR(af[0][0], BASE, (H)*16384 + 0);                                \
        DSR(af[0][1], BASE, (H)*16384 + 1024);                             \
        DSR(af[0][2], BASE, (H)*16384 + 2048);                             \
        DSR(af[0][3], BASE, (H)*16384 + 3072);                             \
        DSR(af[1][0], BASE, (H)*16384 + 4096);                             \
        DSR(af[1][1], BASE, (H)*16384 + 5120);                             \
        DSR(af[1][2], BASE, (H)*16384 + 6144);                             \
        DSR(af[1][3], BASE, (H)*16384 + 7168);                             \
    } while (0)

// 4 B reads: kk0..3
#define LDGB(dst, BASE, H) do {                                            \
        DSR(dst[0], BASE, (H)*16384 + 0);                                  \
        DSR(dst[1], BASE, (H)*16384 + 1024);                               \
        DSR(dst[2], BASE, (H)*16384 + 2048);                               \
        DSR(dst[3], BASE, (H)*16384 + 3072);                               \
    } while (0)

#define MFMA32(A8, B8, ACC)                                                \
    ACC = __builtin_amdgcn_mfma_f32_32x32x16_f16(A8, B8, ACC, 0, 0, 0)

// 4 MFMAs: one mm, kk 0..3
#define MMA_MM(QA, QB, MM, BF) do {                                        \
        __builtin_amdgcn_s_setprio(1);                                     \
        MFMA32(af[MM][0], BF[0], acc[QA][QB][MM]);                         \
        MFMA32(af[MM][1], BF[1], acc[QA][QB][MM]);                         \
        MFMA32(af[MM][2], BF[2], acc[QA][QB][MM]);                         \
        MFMA32(af[MM][3], BF[3], acc[QA][QB][MM]);                         \
        __builtin_amdgcn_s_setprio(0);                                     \
    } while (0)

// 4 MFMAs: both mm, two kk values (for the B-gated split in P1)
#define MMA_KK(QA, QB, K0, K1, BF) do {                                    \
        __builtin_amdgcn_s_setprio(1);                                     \
        MFMA32(af[0][K0], BF[K0], acc[QA][QB][0]);                         \
        MFMA32(af[1][K0], BF[K0], acc[QA][QB][1]);                         \
        MFMA32(af[0][K1], BF[K1], acc[QA][QB][0]);                         \
        MFMA32(af[1][K1], BF[K1], acc[QA][QB][1]);                         \
        __builtin_amdgcn_s_setprio(0);                                     \
    } while (0)

// counted lgkm wait + scheduler fence (rule #18 — required)
#define WAITL(NLIT)                                                        \
    asm volatile("s_waitcnt lgkmcnt(" NLIT ")");                           \
    __builtin_amdgcn_sched_barrier(0)

// bare barrier (m141: no blanket scheduler pinning)
#define BARS()                                                             \
    __builtin_amdgcn_s_barrier()

#define TILE_FULL(ABASE, BBASE, BBASEn, CURB, NXTB, kt, SU, SV)            \
    /* P0: MFMA(A0,B0=SU); af<-A0; stage B0(t+1)->nxt */                   \
    LDGA(ABASE, 0); STAGE_B(NXTB, 0, (kt) + 1);                            \
    WAITL("4"); MMA_MM(0, 0, 0, SU);                                       \
    WAITL("0"); MMA_MM(0, 0, 1, SU);                                       \
    BARS();                                                                \
    /* P1: MFMA(A0,B1=SV); B1 reads; stage A0(t+2)->cur */                 \
    LDGB(SV, BBASE, 1); STAGE_A(CURB, 0, (kt) + 2);                        \
    WAITL("2"); MMA_KK(0, 1, 0, 1, SV);                                    \
    WAITL("0"); MMA_KK(0, 1, 2, 3, SV);                                    \
    BARS();                                                                \
    /* P2: MFMA(A1,B1); af<-A1; stage B1(t+2)->cur */                      \
    LDGA(ABASE, 1); STAGE_B(CURB, 1, (kt) + 2);                            \
    WAITL("4"); MMA_MM(1, 1, 0, SV);                                       \
    WAITL("0"); MMA_MM(1, 1, 1, SV);                                       \
    BARS();                                                                \
    /* P3: stage A1(t+2); confirm t+1; pre-read B0(t+1)->SV; MFMA(A1,B0) */\
    STAGE_A(CURB, 1, (kt) + 2);                                            \
    asm volatile("s_waitcnt vmcnt(6)");                                    \
    BARS();                                                                \
    LDGB(SV, BBASEn, 0);                                                   \
    MMA_MM(1, 0, 0, SU); MMA_MM(1, 0, 1, SU);                              \
    BARS();

    // ---- prologue: stage tile0 fully + tile1 (A0,B1,A1); B0(1) in-loop ----
    STAGE_A(0, 0, 0); STAGE_B(0, 0, 0); STAGE_B(0, 1, 0); STAGE_A(0, 1, 0);
    STAGE_A(1, 0, 1); STAGE_B(1, 1, 1); STAGE_A(1, 1, 1);
    asm volatile("s_waitcnt vmcnt(6)");   // tile0 fully arrived
    BARS();
    LDGB(bfP, baseB0, 0);                 // B0(0) -> P (4 carried)

    const int nt = K >> 6;              // even, >= 4 (guarded by launcher)
    for (int kt = 0; kt + 3 < nt; kt += 2) {
        TILE_FULL(baseA0, baseB0, baseB1, 0, 1, kt,     bfP, bfQ);
        TILE_FULL(baseA1, baseB1, baseB0, 1, 0, kt + 1, bfQ, bfP);
    }

    // ---- tile nt-2 (buf0, SU=P, SV=Q): stage only B0(nt-1) ----
    LDGA(baseA0, 0); STAGE_B(1, 0, nt - 1);
    WAITL("4"); MMA_MM(0, 0, 0, bfP);
    WAITL("0"); MMA_MM(0, 0, 1, bfP);
    BARS();
    LDGB(bfQ, baseB0, 1);
    WAITL("2"); MMA_KK(0, 1, 0, 1, bfQ);
    WAITL("0"); MMA_KK(0, 1, 2, 3, bfQ);
    BARS();
    LDGA(baseA0, 1);
    WAITL("4"); MMA_MM(1, 1, 0, bfQ);
    WAITL("0"); MMA_MM(1, 1, 1, bfQ);
    BARS();
    asm volatile("s_waitcnt vmcnt(0)");
    BARS();
    LDGB(bfQ, baseB1, 0);                 // B0(nt-1) -> Q
    MMA_MM(1, 0, 0, bfP); MMA_MM(1, 0, 1, bfP);
    BARS();

    // ---- tile nt-1 (buf1, SU=Q, SV=P): pure compute ----
    LDGA(baseA1, 0);
    WAITL("4"); MMA_MM(0, 0, 0, bfQ);
    WAITL("0"); MMA_MM(0, 0, 1, bfQ);
    BARS();
    LDGB(bfP, baseB1, 1);
    WAITL("2"); MMA_KK(0, 1, 0, 1, bfP);
    WAITL("0"); MMA_KK(0, 1, 2, 3, bfP);
    BARS();
    LDGA(baseA1, 1);
    WAITL("4"); MMA_MM(1, 1, 0, bfP);
    WAITL("0"); MMA_MM(1, 1, 1, bfP);
    BARS();
    MMA_MM(1, 0, 0, bfQ); MMA_MM(1, 0, 1, bfQ);

    // ---- epilogue: 32x32 C/D layout (m74/m101, R11-verified):
    //      col=lane&31, row=(reg&3)+8*(reg>>2)+4*(lane>>5). bias fp16. ----
    float bv[2];
#pragma unroll
    for (int qb = 0; qb < 2; ++qb)
        bv[qb] = __half2float(qcvt(bias[tile_n + qb * 128 + wc * 32 + lr]));

#pragma unroll
    for (int qa = 0; qa < 2; ++qa)
#pragma unroll
        for (int qb = 0; qb < 2; ++qb)
#pragma unroll
            for (int mm = 0; mm < 2; ++mm) {
                const int rowb = tile_m + qa * 128 + wr * 64 + mm * 32 + 4 * hi;
                const int col  = tile_n + qb * 128 + wc * 32 + lr;
#pragma unroll
                for (int g = 0; g < 4; ++g)
#pragma unroll
                    for (int s = 0; s < 4; ++s)
                        C[(size_t)(rowb + g * 8 + s) * N + col] =
                            acc[qa][qb][mm][g * 4 + s] + bv[qb];
            }

#undef STAGE_A
#undef STAGE_B
#undef DSR
#undef LDGA
#undef LDGB
#undef MFMA32
#undef MMA_MM
#undef MMA_KK
#undef WAITL
#undef BARS
#undef TILE_FULL
}

// ---------------------------------------------------------------------------
// Insurance fallback (shape or ws mismatch): fused naive, slow but correct.
// ---------------------------------------------------------------------------
__global__ void qat_gemm_naive(const float* __restrict__ A,
                               const float* __restrict__ B,
                               const float* __restrict__ bias,
                               float* __restrict__ C, int M, int N, int K) {
    const int col = blockIdx.x * blockDim.x + threadIdx.x;
    const int row = blockIdx.y;
    if (col >= N || row >= M) return;
    float s = 0.f;
    for (int k = 0; k < K; ++k) {
        float a = __half2float(qcvt(A[(size_t)row * K + k]));
        float b = __half2float(qcvt(B[(size_t)col * K + k]));
        s += a * b;
    }
    C[(size_t)row * N + col] = s + __half2float(qcvt(bias[col]));
}

// ---------------------------------------------------------------------------
extern "C" void kernel_launch(void* const* d_in, const int* in_sizes, int n_in,
                              void* d_out, int out_size, void* d_ws,
                              size_t ws_size, hipStream_t stream) {
    const float* x = (const float*)d_in[0];
    const float* w = (const float*)d_in[1];
    const float* b = (const float*)d_in[2];
    float* out = (float*)d_out;

    const int xn = in_sizes[0];     // M*K
    const int wn = in_sizes[1];     // N*K
    const int N  = in_sizes[2];     // 4096
    const int K  = wn / N;          // 4096
    const int M  = xn / K;          // 8192

    const size_t need = (size_t)(xn + wn) * sizeof(__half);
    const bool ok = (M % 256 == 0) && (N % 256 == 0) &&
                    (K % 128 == 0) && (K >= 256);

    if (ws_size >= need && ok) {
        __half* xq = (__half*)d_ws;
        __half* wq = xq + xn;

        const int x4 = xn / 4, w4 = wn / 4;
        int blk = ((x4 + w4) + 255) / 256; if (blk > 2048) blk = 2048;
        quant_xw_f32_to_f16<<<blk, 256, 0, stream>>>(x, x4, w, w4, xq, wq);

        dim3 grid((M / 256) * (N / 256));
        gemm_f16_fragorder<<<grid, 512, 0, stream>>>(xq, wq, b, out, M, N, K);
    } else {
        dim3 grid((N + 255) / 256, M);
        qat_gemm_naive<<<grid, 256, 0, stream>>>(x, w, b, out, M, N, K);
    }
}